// Round 9
// baseline (332.677 us; speedup 1.0000x reference)
//
#include <hip/hip_runtime.h>

#define NB 8
#define NP 24564
#define NCLS 80          // foreground classes
#define TOPK 400
#define KEEPK 200
#define OUTS 19
#define NCELL (OUTS * OUTS)   // 361
#define DETN (NCLS * TOPK)    // 32000 per batch
#define CKS 32008             // compact-key stride per batch
#define ROWS 64
#define CHUNKS ((NP + ROWS - 1) / ROWS)   // 384
#define CAP 1024
#define T0 0.972f   // collection gate: E[count]=688 sd 26 -> count in [400,1024] w.h.p.
#define SLOTS 12    // per (chunk,class) capacity: P(Poisson(1.8) > 12) ~ 1e-9
#define SLOTN (CHUNKS * SLOTS)   // 4608 slots per (b,c)

__device__ __forceinline__ unsigned f2ord(float f) {
    unsigned u = __float_as_uint(f);
    return (u & 0x80000000u) ? ~u : (u | 0x80000000u);
}
__device__ __forceinline__ float ord2f(unsigned k) {
    unsigned u = (k & 0x80000000u) ? (k & 0x7fffffffu) : ~k;
    return __uint_as_float(u);
}
// 1024 bins over key top-16-bits; valid scores (0.01,1] map to [0x23,0x380].
__device__ __forceinline__ unsigned bin16(unsigned key) {
    int b = (int)(key >> 16) - 0xBC00;
    b = b < 0 ? 0 : (b > 1023 ? 1023 : b);
    return (unsigned)b;
}

// ---- bitonic sort of 1024 desc (FALLBACK PATH ONLY) ----
__device__ __forceinline__ void cex(unsigned long long* cand, unsigned i, unsigned l, unsigned k) {
    unsigned long long a = cand[i], b = cand[l];
    bool sw = ((i & k) == 0) ? (a < b) : (a > b);
    if (sw) { cand[i] = b; cand[l] = a; }
}
__device__ void sort1024(unsigned long long* cand, int tid) {
    for (unsigned k = 2; k <= 1024; k <<= 1)
        for (unsigned j = k >> 1; j; j >>= 1) {
            for (unsigned i = tid; i < 1024; i += 256) {
                unsigned l = i ^ j;
                if (l > i) cex(cand, i, l, k);
            }
            __syncthreads();
        }
}

// ------- kA: decode boxes + slot-collect (no zero-fill, counts exact) ------
__global__ __launch_bounds__(256) void kA(const float* __restrict__ x,
                                          float4* __restrict__ boxes,
                                          unsigned long long* __restrict__ gcand,
                                          unsigned* __restrict__ gcnts,
                                          unsigned* __restrict__ cnt) {
    int blk = blockIdx.x;
    if (blk == 0 && threadIdx.x < NB * 16) cnt[threadIdx.x] = 0u;
    int b = blk / CHUNKS, chunk = blk % CHUNKS;
    int p0 = chunk * ROWS;
    int nrows = NP - p0; if (nrows > ROWS) nrows = ROWS;
    __shared__ float tile[ROWS * 93];
    const float* src = x + (size_t)(b * NP + p0) * 93;
    int total4 = (nrows * 93) >> 2;          // 64*93 and 52*93 both %4==0
    const float4* s4 = (const float4*)src;
    float4* t4 = (float4*)tile;
    for (int e = threadIdx.x; e < total4; e += 256) t4[e] = s4[e];
    __syncthreads();
    int row = threadIdx.x & 63;              // lane == row
    int lane = row;
    int cg = threadIdx.x >> 6;
    unsigned p = (unsigned)(p0 + row);
    bool rowOk = row < nrows;
    for (int c = cg; c < NCLS; c += 4) {     // c uniform per wave
        float v = rowOk ? tile[row * 93 + 5 + c] : -1.0f;
        bool pred = v > T0;
        unsigned long long bal = __ballot(pred);
        unsigned cc = (unsigned)__popcll(bal);
        unsigned rank = (unsigned)__popcll(bal & ((1ull << lane) - 1ull));
        if (pred && rank < SLOTS)
            gcand[((size_t)(b * NCLS + c) * CHUNKS + chunk) * SLOTS + rank] =
                ((unsigned long long)f2ord(v) << 32) | (unsigned)(~p);
        if (lane == 0)
            gcnts[(size_t)(b * NCLS + c) * CHUNKS + chunk] = cc;
    }
    if (threadIdx.x < nrows) {
        const float* r = tile + threadIdx.x * 93;
        float l0 = r[0], l1 = r[1], l2 = r[2], l3 = r[3];
        float px1 = r[85], py1 = r[86], px2 = r[87], py2 = r[88];
        float v0 = r[89], v1 = r[90], v2 = r[91], v3 = r[92];
        float pw = px2 - px1, ph = py2 - py1;
        float pcx = 0.5f * (px2 + px1), pcy = 0.5f * (py2 + py1);
        float cx = l0 * pw * v0 + pcx;
        float cy = l1 * pw * v1 + pcy;      // reference uses pw here too
        float w = expf(l2 * v2) * pw;
        float h = expf(l3 * v3) * ph;
        float x1 = fminf(fmaxf(cx - 0.5f * w, 0.f), 1.f);
        float y1 = fminf(fmaxf(cy - 0.5f * h, 0.f), 1.f);
        float x2 = fminf(fmaxf(cx + 0.5f * w, 0.f), 1.f);
        float y2 = fminf(fmaxf(cy + 0.5f * h, 0.f), 1.f);
        boxes[(size_t)b * NP + p0 + threadIdx.x] = make_float4(x1, y1, x2, y2);
    }
}

// --- exact fallback select: strided masked read of x, hist1024 + refine ----
__device__ void select_strided(const float* __restrict__ src, unsigned needed,
                               unsigned long long* cand,
                               unsigned* hist, unsigned* aux, unsigned* scal,
                               int tid) {
    for (int i = tid; i < 1024; i += 256) hist[i] = 0u;
    if (tid == 0) { scal[0] = 0u; scal[1] = 0u; scal[2] = 0u; scal[3] = 0u; }
    __syncthreads();
    for (int p = tid; p < NP; p += 256) {
        float v = src[(size_t)p * 93];
        float m = (v > 0.01f) ? v : -1.0f;
        atomicAdd(&hist[bin16(f2ord(m))], 1u);
    }
    __syncthreads();
    unsigned h0 = hist[4 * tid], h1 = hist[4 * tid + 1];
    unsigned h2 = hist[4 * tid + 2], h3 = hist[4 * tid + 3];
    aux[tid] = h0 + h1 + h2 + h3;
    __syncthreads();
    for (int d = 1; d < 256; d <<= 1) {
        unsigned v = (tid + d < 256) ? aux[tid + d] : 0u;
        __syncthreads();
        aux[tid] += v;
        __syncthreads();
    }
    unsigned above = (tid < 255) ? aux[tid + 1] : 0u;
    unsigned s3 = above + h3, s2 = s3 + h2, s1 = s2 + h1, s0 = s1 + h0;
    if (s0 >= needed && s1 < needed) { scal[0] = 4 * tid;     scal[1] = s1;    scal[2] = s0; }
    if (s1 >= needed && s2 < needed) { scal[0] = 4 * tid + 1; scal[1] = s2;    scal[2] = s1; }
    if (s2 >= needed && s3 < needed) { scal[0] = 4 * tid + 2; scal[1] = s3;    scal[2] = s2; }
    if (s3 >= needed && above < needed) { scal[0] = 4 * tid + 3; scal[1] = above; scal[2] = s3; }
    __syncthreads();
    unsigned cb = scal[0], countHigh = scal[1], countAt = scal[2];
    unsigned cut8 = 0;
    if (countAt > CAP) {
        aux[tid] = 0u;
        __syncthreads();
        for (int p = tid; p < NP; p += 256) {
            float v = src[(size_t)p * 93];
            float m = (v > 0.01f) ? v : -1.0f;
            unsigned k = f2ord(m);
            if (bin16(k) == cb) atomicAdd(&aux[(k >> 8) & 255u], 1u);
        }
        __syncthreads();
        for (int d = 1; d < 256; d <<= 1) {
            unsigned v = (tid + d < 256) ? aux[tid + d] : 0u;
            __syncthreads();
            aux[tid] += v;
            __syncthreads();
        }
        unsigned suf8 = aux[tid];
        unsigned sufN = (tid < 255) ? aux[tid + 1] : 0u;
        unsigned need2 = needed - countHigh;
        if (suf8 >= need2 && sufN < need2) scal[3] = (unsigned)tid;
        __syncthreads();
        cut8 = scal[3];
    }
    __syncthreads();
    if (tid == 0) scal[1] = 0u;
    __syncthreads();
    for (int p = tid; p < NP; p += 256) {
        float v = src[(size_t)p * 93];
        float m = (v > 0.01f) ? v : -1.0f;
        unsigned key = f2ord(m);
        unsigned b16 = bin16(key);
        bool take = (b16 > cb) || (b16 == cb && ((key >> 8) & 255u) >= cut8);
        if (take) {
            unsigned pos = atomicAdd(&scal[1], 1u);
            if (pos < CAP) cand[pos] = ((unsigned long long)key << 32) | (unsigned)(~p);
        }
    }
    __syncthreads();
    unsigned cc = scal[1]; if (cc > CAP) cc = CAP;
    for (unsigned i = tid; i < CAP; i += 256) if (i >= cc) cand[i] = 0ull;
    __syncthreads();
    sort1024(cand, tid);
}

// -------- kNms: gather, rank-scatter, triangular IoU, NMS, compact ---------
struct FallbackLDS { unsigned long long cand[CAP]; unsigned hist[1024]; unsigned aux[256]; };
union SelU { unsigned iouRow[TOPK][13]; FallbackLDS f; };
struct HistU { unsigned hist[1024]; unsigned aux[256]; };

__global__ __launch_bounds__(256) void kNms(const float* __restrict__ x,
                                            const float4* __restrict__ boxes,
                                            const unsigned long long* __restrict__ gcand,
                                            const unsigned* __restrict__ gcnts,
                                            unsigned long long* __restrict__ ckeys,
                                            float4* __restrict__ cboxes,
                                            unsigned* __restrict__ cnt) {
    __shared__ unsigned long long cand2[TOPK];   // sorted (by construction) keys
    __shared__ float4 selBox[TOPK];
    __shared__ float selArea[TOPK];
    __shared__ unsigned scal[4];
    __shared__ unsigned keptWords[13];
    __shared__ SelU U;

    int b = blockIdx.x / NCLS, c = blockIdx.x % NCLS;
    int tid = threadIdx.x;
    const unsigned* mycnts = gcnts + (size_t)(b * NCLS + c) * CHUNKS;
    const unsigned long long* gslots = gcand + (size_t)(b * NCLS + c) * SLOTN;

    // fused count-check + gather (thread-per-chunk, copies exactly cc slots)
    if (tid == 0) { scal[1] = 0u; scal[2] = 0u; }
    __syncthreads();
    for (int ch = tid; ch < CHUNKS; ch += 256) {
        unsigned cc = mycnts[ch];
        if (cc > SLOTS) { scal[2] = 1u; cc = SLOTS; }
        if (cc) {
            unsigned base = atomicAdd(&scal[1], cc);
            const unsigned long long* sp = gslots + (size_t)ch * SLOTS;
            for (unsigned s = 0; s < cc; ++s) {
                unsigned d = base + s;
                if (d < CAP) U.f.cand[d] = sp[s];
            }
        }
    }
    __syncthreads();
    unsigned total = scal[1];
    bool fast = (scal[2] == 0u) && (total >= TOPK) && (total <= CAP);

    if (fast) {
        // rank-by-counting: 1 barrier, broadcast LDS reads, no dep chains
        unsigned long long K0 = 0, K1 = 0, K2 = 0, K3 = 0;
        unsigned r0 = 0, r1 = 0, r2 = 0, r3 = 0;
        int n = (int)total;
        if (tid       < n) K0 = U.f.cand[tid];
        if (tid + 256 < n) K1 = U.f.cand[tid + 256];
        if (tid + 512 < n) K2 = U.f.cand[tid + 512];
        if (tid + 768 < n) K3 = U.f.cand[tid + 768];
#pragma unroll 4
        for (int j = 0; j < n; ++j) {
            unsigned long long Kj = U.f.cand[j];
            r0 += (Kj > K0); r1 += (Kj > K1); r2 += (Kj > K2); r3 += (Kj > K3);
        }
        if (tid       < n && r0 < TOPK) cand2[r0] = K0;
        if (tid + 256 < n && r1 < TOPK) cand2[r1] = K1;
        if (tid + 512 < n && r2 < TOPK) cand2[r2] = K2;
        if (tid + 768 < n && r3 < TOPK) cand2[r3] = K3;
    } else {    // exact fallback (probability ~1e-9)
        select_strided(x + (size_t)b * NP * 93 + 5 + c, TOPK,
                       U.f.cand, U.f.hist, U.f.aux, scal, tid);
        for (int k = tid; k < TOPK; k += 256) cand2[k] = U.f.cand[k];
    }
    __syncthreads();

    for (int k = tid; k < TOPK; k += 256) {
        unsigned idx = ~(unsigned)cand2[k];
        if (idx >= NP) idx = 0;
        float4 bx = boxes[(size_t)b * NP + idx];
        selBox[k] = bx;
        selArea[k] = (bx.z - bx.x) * (bx.w - bx.y);
    }
    __syncthreads();

    // triangular IoU (overwrites U.f.cand region -- dead after rank phase):
    // row r computes words 0..(r>>5); garbage above ANDed vs zero kept bits.
#pragma unroll 1
    for (int pass = 0; pass < 2; ++pass) {
        int r = (pass == 0) ? tid : 399 - tid;
        if (pass == 1 && tid >= 144) break;
        float4 br = selBox[r];
        float ar = selArea[r];
        int nw = (r >> 5) + 1;
        for (int w = 0; w < nw; ++w) {
            unsigned word = 0;
#pragma unroll 8
            for (int jj = 0; jj < 32; ++jj) {
                int j = w * 32 + jj;
                float4 bj = selBox[j];
                float ix = fminf(br.z, bj.z) - fmaxf(br.x, bj.x);
                float iy = fminf(br.w, bj.w) - fmaxf(br.y, bj.y);
                float inter = fmaxf(ix, 0.f) * fmaxf(iy, 0.f);
                float uni = ar + selArea[j] - inter;
                word |= (unsigned)(inter > 0.45f * uni) << jj;
            }
            U.iouRow[r][w] = word;
        }
    }
    __syncthreads();

    size_t bb = (size_t)b * DETN;
    if (tid < 64) {                        // wave 0: NMS scan w/ prefetch
        unsigned ln = (unsigned)tid;
        unsigned myKept = 0;
        const unsigned VALID_KEY = f2ord(0.01f);
        unsigned w = (ln < 13) ? U.iouRow[0][ln] : 0u;
        for (int i = 0; i < TOPK; ++i) {
            unsigned wn = (i < TOPK - 1 && ln < 13) ? U.iouRow[i + 1][ln] : 0u;
            bool hit = (w & myKept) != 0u;
            unsigned long long bal = __ballot(hit);
            unsigned keyi = (unsigned)(cand2[i] >> 32);
            bool kept = (keyi > VALID_KEY) && (bal == 0ull);
            if (kept && ln == (unsigned)(i >> 5)) myKept |= 1u << (i & 31);
            w = wn;
        }
        if (ln < 13) keptWords[ln] = myKept;
    } else {                               // waves 1-3: cboxes stores overlap
        for (int k = tid - 64; k < TOPK; k += 192)
            cboxes[bb + (size_t)(c * TOPK + k)] = selBox[k];
    }
    __syncthreads();

    // epilogue: ONE reservation atomic per block, rank-indexed writes
    if (tid == 0) {
        unsigned t2 = 0;
        for (int w = 0; w < 13; ++w) t2 += __popc(keptWords[w]);
        scal[0] = atomicAdd(&cnt[b * 16], t2);
    }
    __syncthreads();
    unsigned base2 = scal[0];
    size_t kb = (size_t)b * CKS;
    for (int k = tid; k < TOPK; k += 256) {
        bool kept = (keptWords[k >> 5] >> (k & 31)) & 1u;
        if (kept) {
            unsigned rank = 0;
            int wi = k >> 5;
            for (int w = 0; w < wi; ++w) rank += __popc(keptWords[w]);
            rank += __popc(keptWords[wi] & ((1u << (k & 31)) - 1u));
            unsigned key = (unsigned)(cand2[k] >> 32);
            unsigned flat = (unsigned)(c * TOPK + k);
            ckeys[kb + base2 + rank] = ((unsigned long long)key << 32) | (unsigned)(~flat);
        }
    }
}

// -------- kC: per-batch top-200 via cut + rank-scatter + rasterize ---------
__global__ __launch_bounds__(256) void kC(const unsigned long long* __restrict__ ckeys,
                                          const float4* __restrict__ cboxes,
                                          const unsigned* __restrict__ cnt,
                                          float* __restrict__ out) {
    __shared__ unsigned long long cand[CAP];
    __shared__ HistU S;
    __shared__ unsigned scal[4];
    __shared__ float eS[KEEPK];
    __shared__ int eC0[KEEPK], eC1[KEEPK], eC2[KEEPK], eC3[KEEPK];
    __shared__ int eCh[KEEPK];

    int b = blockIdx.x;
    int tid = threadIdx.x;
    const unsigned long long* keys = ckeys + (size_t)b * CKS;
    int n = (int)cnt[b * 16]; if (n > DETN) n = DETN;
    const unsigned needed = KEEPK;

    if (tid < KEEPK) eS[tid] = -1.0f;
    for (int i = tid; i < 1024; i += 256) S.hist[i] = 0u;
    if (tid == 0) { scal[0] = 0u; scal[1] = 0u; scal[2] = 0u; scal[3] = 0u; }
    __syncthreads();
    for (int i = tid; i < n; i += 256)
        atomicAdd(&S.hist[bin16((unsigned)(keys[i] >> 32))], 1u);
    __syncthreads();
    unsigned h0 = S.hist[4 * tid], h1 = S.hist[4 * tid + 1];
    unsigned h2 = S.hist[4 * tid + 2], h3 = S.hist[4 * tid + 3];
    S.aux[tid] = h0 + h1 + h2 + h3;
    __syncthreads();
    for (int d = 1; d < 256; d <<= 1) {
        unsigned v = (tid + d < 256) ? S.aux[tid + d] : 0u;
        __syncthreads();
        S.aux[tid] += v;
        __syncthreads();
    }
    unsigned above = (tid < 255) ? S.aux[tid + 1] : 0u;
    unsigned s3 = above + h3, s2 = s3 + h2, s1 = s2 + h1, s0 = s1 + h0;
    if (s0 >= needed && s1 < needed) { scal[0] = 4 * tid;     scal[1] = s1;    scal[2] = s0; }
    if (s1 >= needed && s2 < needed) { scal[0] = 4 * tid + 1; scal[1] = s2;    scal[2] = s1; }
    if (s2 >= needed && s3 < needed) { scal[0] = 4 * tid + 2; scal[1] = s3;    scal[2] = s2; }
    if (s3 >= needed && above < needed) { scal[0] = 4 * tid + 3; scal[1] = above; scal[2] = s3; }
    __syncthreads();
    unsigned cb = scal[0], countHigh = scal[1], countAt = scal[2];
    unsigned cut8 = 0;
    if (countAt > CAP) {   // byte refine on key[15:8] within cut bin (MANDATORY path)
        S.aux[tid] = 0u;
        __syncthreads();
        for (int i = tid; i < n; i += 256) {
            unsigned kx = (unsigned)(keys[i] >> 32);
            if (bin16(kx) == cb) atomicAdd(&S.aux[(kx >> 8) & 255u], 1u);
        }
        __syncthreads();
        for (int d = 1; d < 256; d <<= 1) {
            unsigned v = (tid + d < 256) ? S.aux[tid + d] : 0u;
            __syncthreads();
            S.aux[tid] += v;
            __syncthreads();
        }
        unsigned suf8 = S.aux[tid];
        unsigned sufN = (tid < 255) ? S.aux[tid + 1] : 0u;
        unsigned need2 = needed - countHigh;
        if (suf8 >= need2 && sufN < need2) scal[3] = (unsigned)tid;
        __syncthreads();
        cut8 = scal[3];
    }
    __syncthreads();
    if (tid == 0) scal[1] = 0u;
    __syncthreads();
    for (int i = tid; i < n; i += 256) {
        unsigned long long key = keys[i];
        unsigned kh = (unsigned)(key >> 32);
        unsigned b16 = bin16(kh);
        bool take = (b16 > cb) || (b16 == cb && ((kh >> 8) & 255u) >= cut8);
        if (take) {
            unsigned pos = atomicAdd(&scal[1], 1u);
            if (pos < CAP) cand[pos] = key;
        }
    }
    __syncthreads();
    int cc = (int)scal[1]; if (cc > CAP) cc = CAP;

    // rank-by-counting scatter straight into the epilogue arrays
    {
        unsigned long long K0 = 0, K1 = 0, K2 = 0, K3 = 0;
        unsigned r0 = 0, r1 = 0, r2 = 0, r3 = 0;
        if (tid       < cc) K0 = cand[tid];
        if (tid + 256 < cc) K1 = cand[tid + 256];
        if (tid + 512 < cc) K2 = cand[tid + 512];
        if (tid + 768 < cc) K3 = cand[tid + 768];
#pragma unroll 4
        for (int j = 0; j < cc; ++j) {
            unsigned long long Kj = cand[j];
            r0 += (Kj > K0); r1 += (Kj > K1); r2 += (Kj > K2); r3 += (Kj > K3);
        }
#pragma unroll
        for (int q = 0; q < 4; ++q) {
            unsigned long long K = q == 0 ? K0 : q == 1 ? K1 : q == 2 ? K2 : K3;
            unsigned r = q == 0 ? r0 : q == 1 ? r1 : q == 2 ? r2 : r3;
            int i = tid + q * 256;
            if (i < cc && r < KEEPK) {
                unsigned flat = ~(unsigned)K;
                if (flat >= DETN) flat = 0;
                float4 bx = cboxes[(size_t)b * DETN + flat];
                eS[r] = ord2f((unsigned)(K >> 32));
                eC0[r] = (int)rintf(bx.x * (float)OUTS);
                eC1[r] = (int)rintf(bx.y * (float)OUTS);
                eC2[r] = (int)rintf(bx.z * (float)OUTS);
                eC3[r] = (int)rintf(bx.w * (float)OUTS);
                eCh[r] = (int)(flat / TOPK);
            }
        }
    }
    __syncthreads();

    for (int cell = tid; cell < NCELL; cell += 256) {
        int y = cell / OUTS, x = cell % OUTS;
        float* o = out + ((size_t)b * NCELL + cell) * 81;
        for (int ch = 0; ch < 81; ++ch) o[ch] = 0.f;
        for (int k = 0; k < KEEPK; ++k) {
            float s = eS[k];
            if (s < 0.6f) continue;
            if (y >= eC1[k] && y < eC3[k] && x >= eC0[k] && x < eC2[k])
                o[eCh[k]] = s;
        }
    }
}

extern "C" void kernel_launch(void* const* d_in, const int* in_sizes, int n_in,
                              void* d_out, int out_size, void* d_ws, size_t ws_size,
                              hipStream_t stream) {
    const float* x = (const float*)d_in[0];
    float* out = (float*)d_out;

    float4* boxes   = (float4*)d_ws;                          // NB*NP
    float4* cboxes  = boxes + (size_t)NB * NP;                // NB*DETN
    unsigned long long* ckeys = (unsigned long long*)(cboxes + (size_t)NB * DETN); // NB*CKS
    unsigned long long* gcand = ckeys + (size_t)NB * CKS;     // NB*NCLS*SLOTN
    unsigned* gcnts = (unsigned*)(gcand + (size_t)NB * NCLS * SLOTN);  // NB*NCLS*CHUNKS
    unsigned* cnt   = gcnts + (size_t)NB * NCLS * CHUNKS;     // NB*16 (padded)

    kA<<<NB * CHUNKS, 256, 0, stream>>>(x, boxes, gcand, gcnts, cnt);
    kNms<<<NB * NCLS, 256, 0, stream>>>(x, boxes, gcand, gcnts, ckeys, cboxes, cnt);
    kC<<<NB, 256, 0, stream>>>(ckeys, cboxes, cnt, out);
}